// Round 1
// baseline (872.486 us; speedup 1.0000x reference)
//
#include <hip/hip_runtime.h>
#include <math.h>

#define NMS_THRESH 0.7f
#define NANCH 36864
#define TOPK 6000
#define NWORDS 94    // ceil(6000/64)
#define POSTK 300

// ---------------- conv 3x3 + bias + relu, batch 0 only ----------------
// grid 256 = co_tile(8) * sp_tile(32); block 256 threads
// per block: 64 c_out x (8 rows x 16 cols) spatial
__global__ __launch_bounds__(256, 2)
void k_conv(const float* __restrict__ feat, const float* __restrict__ W,
            const float* __restrict__ bias, float* __restrict__ tout)
{
    __shared__ float sF[16][10][18];   // ci x (8+2) x (16+2)
    __shared__ float sW[16][9][64];    // ci x tap x co  (co contiguous)

    const int blk = blockIdx.x;
    const int ct  = blk >> 5;          // 0..7
    const int sp  = blk & 31;          // 0..31
    const int ty0 = (sp >> 2) * 8;     // 0..56
    const int tx0 = (sp & 3) * 16;     // 0..48
    const int co0 = ct * 64;
    const int tid = threadIdx.x;
    const int pg  = tid & 31;
    const int cs  = tid >> 5;          // 0..7
    const int row = pg >> 2;           // 0..7
    const int xb  = (pg & 3) * 4;      // 0,4,8,12

    float acc[4][8];
    #pragma unroll
    for (int i = 0; i < 4; ++i)
        #pragma unroll
        for (int j = 0; j < 8; ++j) acc[i][j] = 0.f;

    for (int cc = 0; cc < 32; ++cc) {
        const int ci0 = cc * 16;
        __syncthreads();
        // stage feat halo tile: 16*10*18 = 2880
        for (int idx = tid; idx < 2880; idx += 256) {
            int ci  = idx / 180; int rem = idx - ci * 180;
            int yy  = rem / 18;  int xx  = rem - yy * 18;
            int gy  = ty0 + yy - 1, gx = tx0 + xx - 1;
            float v = 0.f;
            if (gy >= 0 && gy < 64 && gx >= 0 && gx < 64)
                v = feat[(size_t)(ci0 + ci) * 4096 + gy * 64 + gx];
            sF[ci][yy][xx] = v;
        }
        // stage weights: 16*9*64 = 9216 (global-contiguous runs per co)
        for (int idx = tid; idx < 9216; idx += 256) {
            int co = idx / 144; int r = idx - co * 144;
            float v = W[(size_t)(co0 + co) * 4608 + (size_t)ci0 * 9 + r];
            int ci = r / 9; int tap = r - ci * 9;
            sW[ci][tap][co] = v;
        }
        __syncthreads();
        #pragma unroll 1
        for (int ci = 0; ci < 16; ++ci) {
            #pragma unroll
            for (int ky = 0; ky < 3; ++ky) {
                float fr[6];
                #pragma unroll
                for (int u = 0; u < 6; ++u) fr[u] = sF[ci][row + ky][xb + u];
                #pragma unroll
                for (int kx = 0; kx < 3; ++kx) {
                    float wv[8];
                    #pragma unroll
                    for (int j = 0; j < 8; ++j) wv[j] = sW[ci][ky * 3 + kx][cs * 8 + j];
                    #pragma unroll
                    for (int i = 0; i < 4; ++i)
                        #pragma unroll
                        for (int j = 0; j < 8; ++j)
                            acc[i][j] = fmaf(fr[i + kx], wv[j], acc[i][j]);
                }
            }
        }
    }
    const int y = ty0 + row;
    #pragma unroll
    for (int j = 0; j < 8; ++j) {
        const int co = co0 + cs * 8 + j;
        const float bv = bias[co];
        #pragma unroll
        for (int i = 0; i < 4; ++i) {
            float v = fmaxf(acc[i][j] + bv, 0.f);
            tout[(size_t)co * 4096 + y * 64 + tx0 + xb + i] = v;
        }
    }
}

// ---------------- 1x1 heads: 9 cls + 36 reg channels ----------------
// grid 720 = ch(45) * px_block(16); block 256
__global__ __launch_bounds__(256, 4)
void k_heads(const float* __restrict__ t, const float* __restrict__ cls_w,
             const float* __restrict__ cls_b, const float* __restrict__ reg_w,
             const float* __restrict__ reg_b, float* __restrict__ heads)
{
    const int blk = blockIdx.x;
    const int ch  = blk >> 4;                       // 0..44
    const int px  = ((blk & 15) << 8) + threadIdx.x;
    const float* wp; float bv;
    if (ch < 9) { wp = cls_w + ch * 512;       bv = cls_b[ch]; }
    else        { wp = reg_w + (ch - 9) * 512; bv = reg_b[ch - 9]; }
    float acc = bv;
    #pragma unroll 8
    for (int ci = 0; ci < 512; ++ci)
        acc = fmaf(t[(size_t)ci * 4096 + px], wp[ci], acc);
    heads[(size_t)ch * 4096 + px] = acc;
}

// ---------------- per-anchor decode, sigmoid, clip, validity ----------------
__global__ void k_decode(const float* __restrict__ heads,
                         float* __restrict__ score, float* __restrict__ validf,
                         float* __restrict__ box)
{
    int idx = blockIdx.x * 256 + threadIdx.x;
    if (idx >= NANCH) return;
    int p = idx / 9, a = idx - p * 9;
    int yq = p >> 6, xq = p & 63;
    const double scl[3] = {128.0, 256.0, 512.0};
    const double rat[3] = {0.5, 1.0, 2.0};
    double s = scl[a / 3], r = rat[a % 3];
    float bw = (float)(s * sqrt(1.0 / r) * 0.5);   // f64 math -> f32, mirrors ref
    float bh = (float)(s * sqrt(r) * 0.5);
    float sx = xq * 16.0f + 8.0f;
    float sy = yq * 16.0f + 8.0f;
    float a0 = sx - bw, a1 = sy - bh, a2 = sx + bw, a3 = sy + bh;
    float wa = a2 - a0, ha = a3 - a1;
    float cx = a0 + 0.5f * wa, cy = a1 + 0.5f * ha;
    float logit = heads[(size_t)a * 4096 + p];
    float dx = heads[(size_t)(9  + 4 * a) * 4096 + p];
    float dy = heads[(size_t)(10 + 4 * a) * 4096 + p];
    float dw = fminf(heads[(size_t)(11 + 4 * a) * 4096 + p], 4.135166556742356f);
    float dh = fminf(heads[(size_t)(12 + 4 * a) * 4096 + p], 4.135166556742356f);
    float pcx = dx * wa + cx, pcy = dy * ha + cy;
    float pw = expf(dw) * wa, ph = expf(dh) * ha;
    float x1 = pcx - 0.5f * pw, y1 = pcy - 0.5f * ph;
    float x2 = pcx + 0.5f * pw, y2 = pcy + 0.5f * ph;
    x1 = fminf(fmaxf(x1, 0.f), 1024.f); y1 = fminf(fmaxf(y1, 0.f), 1024.f);
    x2 = fminf(fmaxf(x2, 0.f), 1024.f); y2 = fminf(fmaxf(y2, 0.f), 1024.f);
    float wv = x2 - x1, hv = y2 - y1;
    float sc = 1.f / (1.f + expf(-logit));
    score[idx]  = sc;
    validf[idx] = (wv >= 1.f && hv >= 1.f) ? 1.f : 0.f;
    box[idx * 4 + 0] = x1; box[idx * 4 + 1] = y1;
    box[idx * 4 + 2] = x2; box[idx * 4 + 3] = y2;
}

// ---------------- exact top-6000 via rank computation ----------------
// grid 1152; block 256 = 32 i-lanes x 8 j-splits
__global__ __launch_bounds__(256, 4)
void k_rank(const float* __restrict__ score, const float* __restrict__ validf,
            const float* __restrict__ box,
            float* __restrict__ score6, float* __restrict__ sc6,
            float* __restrict__ box6)
{
    __shared__ int pc[8][32];
    const int tid = threadIdx.x;
    const int il = tid & 31, js = tid >> 5;
    const int i = blockIdx.x * 32 + il;
    const float si = score[i];
    const float4* sp = (const float4*)score;
    int cnt = 0;
    const int j0 = js * 4608;
    for (int q = 0; q < 1152; ++q) {
        float4 v = sp[j0 / 4 + q];
        int jb = j0 + q * 4;
        cnt += (v.x > si) || (v.x == si && (jb + 0) < i);
        cnt += (v.y > si) || (v.y == si && (jb + 1) < i);
        cnt += (v.z > si) || (v.z == si && (jb + 2) < i);
        cnt += (v.w > si) || (v.w == si && (jb + 3) < i);
    }
    pc[js][il] = cnt;
    __syncthreads();
    if (js == 0) {
        int rank = 0;
        #pragma unroll
        for (int q = 0; q < 8; ++q) rank += pc[q][il];
        if (rank < TOPK) {
            score6[rank] = si;
            sc6[rank] = (validf[i] != 0.f) ? si : -INFINITY;
            box6[rank * 4 + 0] = box[i * 4 + 0];
            box6[rank * 4 + 1] = box[i * 4 + 1];
            box6[rank * 4 + 2] = box[i * 4 + 2];
            box6[rank * 4 + 3] = box[i * 4 + 3];
        }
    }
}

// ---------------- pairwise IoU bitmask ----------------
// grid 94*94; block 64.  mask[i][w] bit q = IoU(box i, box w*64+q) > thr
__global__ void k_iou(const float* __restrict__ box6,
                      unsigned long long* __restrict__ mask)
{
    __shared__ float jb[64][4];
    const int blk = blockIdx.x;
    const int rb = blk / NWORDS, wb = blk - rb * NWORDS;
    const int tid = threadIdx.x;
    int j = wb * 64 + tid;
    if (j < TOPK) {
        jb[tid][0] = box6[j * 4 + 0]; jb[tid][1] = box6[j * 4 + 1];
        jb[tid][2] = box6[j * 4 + 2]; jb[tid][3] = box6[j * 4 + 3];
    } else {
        jb[tid][0] = 0.f; jb[tid][1] = 0.f; jb[tid][2] = 0.f; jb[tid][3] = 0.f;
    }
    __syncthreads();
    int i = rb * 64 + tid;
    if (i >= TOPK) return;
    float x1 = box6[i * 4], y1 = box6[i * 4 + 1], x2 = box6[i * 4 + 2], y2 = box6[i * 4 + 3];
    float ai = (x2 - x1) * (y2 - y1);
    unsigned long long bits = 0;
    for (int q = 0; q < 64; ++q) {
        float bx1 = jb[q][0], by1 = jb[q][1], bx2 = jb[q][2], by2 = jb[q][3];
        float xl = fmaxf(x1, bx1), yt = fmaxf(y1, by1);
        float xr = fminf(x2, bx2), yb = fminf(y2, by2);
        float inter = fmaxf(xr - xl, 0.f) * fmaxf(yb - yt, 0.f);
        float aj = (bx2 - bx1) * (by2 - by1);
        float iou = inter / (ai + aj - inter);
        if (iou > NMS_THRESH) bits |= (1ull << q);
    }
    mask[(size_t)i * NWORDS + wb] = bits;
}

// ---------------- sequential greedy NMS scan + output ----------------
// single block, 256 threads
__global__ void k_scan(const float* __restrict__ sc6, const float* __restrict__ score6,
                       const float* __restrict__ box6,
                       const unsigned long long* __restrict__ mask,
                       float* __restrict__ out)
{
    __shared__ unsigned long long remv[NWORDS];
    __shared__ int kept[POSTK];
    __shared__ int kcnt;
    __shared__ int kbs_s;
    __shared__ int klist[64];
    const int tid = threadIdx.x;
    for (int w = tid; w < NWORDS; w += 256) remv[w] = 0ull;
    if (tid == 0) kcnt = 0;
    __syncthreads();
    for (int b = 0; b < NWORDS; ++b) {
        if (tid < 64) {
            int i = b * 64 + tid;
            bool v = (i < TOPK) && (sc6[i] > -INFINITY);
            unsigned long long mi = 0ull;
            if (v) mi = mask[(size_t)i * NWORDS + b];
            unsigned long long validb = __ballot(v);
            unsigned long long cur = remv[b];
            int kc = kcnt;
            int kb = 0;
            unsigned long long cand = validb & ~cur;
            while (cand != 0ull && kc < POSTK) {
                int rr = __builtin_ctzll(cand);
                unsigned long long mr = __shfl(mi, rr, 64);
                if (tid == 0) { kept[kc] = b * 64 + rr; klist[kb] = rr; }
                ++kb; ++kc;
                cur |= mr | (1ull << rr);
                cand = validb & ~cur;
            }
            if (tid == 0) { kcnt = kc; kbs_s = kb; remv[b] = cur; }
        }
        __syncthreads();
        int kb = kbs_s;
        if (kb > 0) {
            int w = b + 1 + tid;
            if (w < NWORDS) {
                unsigned long long acc = remv[w];
                for (int q = 0; q < kb; ++q) {
                    int rr = klist[q];
                    acc |= mask[(size_t)(b * 64 + rr) * NWORDS + w];
                }
                remv[w] = acc;
            }
        }
        __syncthreads();
        if (kcnt >= POSTK) break;
    }
    __syncthreads();
    int kc = kcnt;
    for (int n = tid; n < POSTK; n += 256) {
        float o0 = 0.f, o1 = 0.f, o2 = 0.f, o3 = 0.f, o4 = 0.f;
        if (n < kc) {
            int i = kept[n];
            o0 = box6[i * 4 + 0]; o1 = box6[i * 4 + 1];
            o2 = box6[i * 4 + 2]; o3 = box6[i * 4 + 3];
            o4 = score6[i];
        }
        out[n * 5 + 0] = o0; out[n * 5 + 1] = o1; out[n * 5 + 2] = o2;
        out[n * 5 + 3] = o3; out[n * 5 + 4] = o4;
    }
}

extern "C" void kernel_launch(void* const* d_in, const int* in_sizes, int n_in,
                              void* d_out, int out_size, void* d_ws, size_t ws_size,
                              hipStream_t stream)
{
    (void)in_sizes; (void)n_in; (void)out_size; (void)ws_size;
    const float* feat   = (const float*)d_in[1];   // (8,512,64,64) -> batch 0 only
    const float* conv_w = (const float*)d_in[2];
    const float* conv_b = (const float*)d_in[3];
    const float* cls_w  = (const float*)d_in[4];
    const float* cls_b  = (const float*)d_in[5];
    const float* reg_w  = (const float*)d_in[6];
    const float* reg_b  = (const float*)d_in[7];

    char* ws = (char*)d_ws;
    float* t      = (float*)(ws + 0);          // 8,388,608 B (dead after k_heads)
    float* heads  = (float*)(ws + 8388608);    //   737,280 B
    float* score  = (float*)(ws + 9125888);    //   147,456 B
    float* validf = (float*)(ws + 9273344);    //   147,456 B
    float* box    = (float*)(ws + 9420800);    //   589,824 B
    float* score6 = (float*)(ws + 10010624);   //    24,000 B
    float* sc6    = (float*)(ws + 10034624);   //    24,000 B
    float* box6   = (float*)(ws + 10058624);   //    96,000 B
    unsigned long long* mask = (unsigned long long*)(ws + 0); // reuse t: 4,512,000 B

    k_conv  <<<256,  256, 0, stream>>>(feat, conv_w, conv_b, t);
    k_heads <<<720,  256, 0, stream>>>(t, cls_w, cls_b, reg_w, reg_b, heads);
    k_decode<<<144,  256, 0, stream>>>(heads, score, validf, box);
    k_rank  <<<1152, 256, 0, stream>>>(score, validf, box, score6, sc6, box6);
    k_iou   <<<NWORDS * NWORDS, 64, 0, stream>>>(box6, mask);
    k_scan  <<<1,    256, 0, stream>>>(sc6, score6, box6, mask, (float*)d_out);
}